// Round 5
// baseline (233.536 us; speedup 1.0000x reference)
//
#include <hip/hip_runtime.h>
#include <math.h>

// CBOW hierarchical-softmax loss — R5: max memory-level parallelism.
//   B=65536, C=10, D=18, E=128.
//   loss[b] = -sum_d log( p_d + 1e-9 ), p_d = (code==1) ? s_d : 1 - s_d,
//   s_d = sigmoid(u_d . v), v = mean_c in_embed[ctx[b,c]].
//
// R1: p computed literally as fp32 reference (s then 1-s, precise expf/logf).
// R2: VALU-bound -> half-wave split (float4 gathers, 2 rows/inst).
// R3: batched 18 transcendentals into 1 wave pass.
// R4: VALUBusy 23%, dur STILL 131us, VGPR_Count=32 -> compiler serialized
//     the 14 row gathers (56 VGPRs of landing slots don't fit in 32).
// R5: (a) __launch_bounds__(256,6) -> ~85 VGPR budget, (b) wave-uniform b
//     via readfirstlane so index loads become s_load (scalar path),
//     (c) all 14 float4 gathers issued into distinct regs before any math.

constexpr int Bn = 65536;
constexpr int Cn = 10;
constexpr int Dn = 18;
constexpr float EPS = 1e-9f;

__global__ __launch_bounds__(256, 6) void cbow_hs_kernel(
    const int* __restrict__ ctx,          // [B,C]
    const int* __restrict__ nodes,        // [B,D]
    const int* __restrict__ codes,        // [B,D]
    const float* __restrict__ in_embed,   // [V,E]
    const float* __restrict__ node_embed, // [N,E]
    float* __restrict__ out)              // [B]
{
    // wave id made provably wave-uniform -> b uniform -> index loads go
    // through the scalar (s_load) path into SGPRs.
    const int wv   = __builtin_amdgcn_readfirstlane(threadIdx.x >> 6);
    const int lane = threadIdx.x & 63;
    const int sl   = lane & 31;          // sub-lane within half
    const bool hi  = lane >= 32;         // half 0: even c/d, half 1: odd
    const int b    = (blockIdx.x << 2) + wv;

    // ---- wave-uniform index loads (SGPRs, lgkmcnt path) ----
    int cidx[Cn];
    #pragma unroll
    for (int c = 0; c < Cn; ++c) cidx[c] = ctx[b * Cn + c];
    int nidx[Dn];
    #pragma unroll
    for (int d = 0; d < Dn; ++d) nidx[d] = nodes[b * Dn + d];

    const float4* __restrict__ in4 = (const float4*)in_embed;    // 32 f4/row
    const float4* __restrict__ ne4 = (const float4*)node_embed;

    // ---- issue ALL 14 row gathers before any reduction math ----
    // (row offset fits 32-bit: idx*512B < 2^31)
    float4 ce[Cn / 2];
    #pragma unroll
    for (int k = 0; k < Cn / 2; ++k) {
        unsigned idx = (unsigned)(hi ? cidx[2 * k + 1] : cidx[2 * k]);
        ce[k] = in4[(idx << 5) + sl];
    }
    float4 ue[Dn / 2];
    #pragma unroll
    for (int i = 0; i < Dn / 2; ++i) {
        unsigned idx = (unsigned)(hi ? nidx[2 * i + 1] : nidx[2 * i]);
        ue[i] = ne4[(idx << 5) + sl];
    }

    // ---- v = mean of 10 context rows ----
    float4 vs = make_float4(0.f, 0.f, 0.f, 0.f);
    #pragma unroll
    for (int k = 0; k < Cn / 2; ++k) {
        vs.x += ce[k].x; vs.y += ce[k].y; vs.z += ce[k].z; vs.w += ce[k].w;
    }
    vs.x += __shfl_xor(vs.x, 32, 64);
    vs.y += __shfl_xor(vs.y, 32, 64);
    vs.z += __shfl_xor(vs.z, 32, 64);
    vs.w += __shfl_xor(vs.w, 32, 64);
    float4 v;
    v.x = vs.x * (1.0f / Cn); v.y = vs.y * (1.0f / Cn);
    v.z = vs.z * (1.0f / Cn); v.w = vs.w * (1.0f / Cn);

    // ---- 18 dots (9 per half) + 5-level butterfly within each half ----
    float pd[Dn / 2];
    #pragma unroll
    for (int i = 0; i < Dn / 2; ++i)
        pd[i] = ue[i].x * v.x + ue[i].y * v.y + ue[i].z * v.z + ue[i].w * v.w;

    #pragma unroll
    for (int i = 0; i < Dn / 2; ++i) {
        #pragma unroll
        for (int m = 16; m >= 1; m >>= 1)
            pd[i] += __shfl_xor(pd[i], m, 64);
    }

    // ---- epilogue: ONE transcendental pass for all 18 terms ----
    // Lane sl (sl<9) of half hi takes logit for d = 2*sl + hi.
    float myv = 0.f;
    #pragma unroll
    for (int i = 0; i < Dn / 2; ++i)
        myv = (sl == i) ? pd[i] : myv;

    const int d  = 2 * sl + (hi ? 1 : 0);
    const int cd = codes[b * Dn + ((sl < Dn / 2) ? d : 0)];  // L1-hot

    // Literal fp32 reference semantics (precise expf / IEEE div / logf):
    float s = 1.0f / (1.0f + expf(-myv));
    float p = (cd == 1) ? s : 1.0f - s;
    float t = (sl < Dn / 2) ? -logf(p + EPS) : 0.f;

    // tree-sum the 18 terms across the full wave
    #pragma unroll
    for (int m = 32; m >= 1; m >>= 1)
        t += __shfl_xor(t, m, 64);

    if (lane == 0) out[b] = t;
}

extern "C" void kernel_launch(void* const* d_in, const int* in_sizes, int n_in,
                              void* d_out, int out_size, void* d_ws, size_t ws_size,
                              hipStream_t stream) {
    const int*   ctx        = (const int*)d_in[0];
    const int*   path_nodes = (const int*)d_in[1];
    const int*   codes      = (const int*)d_in[2];
    const float* in_embed   = (const float*)d_in[3];
    const float* node_embed = (const float*)d_in[4];
    float*       out        = (float*)d_out;

    dim3 grid(Bn / 4);
    dim3 block(256);
    cbow_hs_kernel<<<grid, block, 0, stream>>>(ctx, path_nodes, codes,
                                               in_embed, node_embed, out);
}